// Round 2
// baseline (5335.553 us; speedup 1.0000x reference)
//
#include <hip/hip_runtime.h>
#include <stdint.h>

// ---------------------------------------------------------------------------
// Fused spiking-MLP forward: 20 timesteps, B=16384, 784 -> 400 -> 10.
//
// RNG: jax threefry, PARTITIONABLE semantics (verified absmax 0.0):
//   key_t = TF((0,42),(0,t)); per element e: bits = x0^x1 of TF(key_t,(0,e));
//   u = bitcast((bits>>9)|0x3f800000)-1.0f; xi = (x > u).
//
// V3 (vs V2 @5274us): the rocprof accounting showed ~40% of each tile's
// wall was a SERIALIZED stage phase (barrier -> ds_write -> barrier) with
// all resident waves idle. Fixes, both numerically bit-identical:
//  * Double-buffered LDS W1 tile: stager writes tile t+1 into buf^1 WHILE
//    everyone consumes buf (disjoint), one barrier per tile. Global
//    prefetch of tile t+2 issued in the same phase -> L2 latency hidden
//    under a full consume phase.
//  * W1 staged as f64 (stager converts once) -> consumer cvt_f64_f32
//    eliminated (~20% of hot-loop VALU). f32->f64 is exact; add order
//    unchanged -> bit-identical membrane sums.
//  * TD=8 so the f64 double-buffer fits 2 blocks/CU (we are register-
//    capped at 2 blocks anyway: 64 f64 accumulator regs/thread).
// Structure otherwise as V2: two timesteps share one W1 sweep; 8 waves =
// 4 sample-groups x 2 neuron-halves; xi bits hoisted to SGPR -> scalar-
// branch-gated f64 adds.
// ---------------------------------------------------------------------------

#define BSZ    16384
#define INDIM  784
#define HID    400
#define ODIM   10
#define TSTEPS 20

#define TD   8            // d-tile size
#define NT   98           // 784/8 tiles per sweep
#define WTJ  512          // padded neuron rows in LDS tile (400 real)
#define XIW  26           // xi words per sample
#define SPW  14           // spike words per sample

__device__ __forceinline__ void tfr(uint32_t& x0, uint32_t& x1, int r) {
  x0 += x1;
  x1 = (x1 << r) | (x1 >> (32 - r));
  x1 ^= x0;
}

__device__ __forceinline__ uint2 tf2x32(uint32_t k0, uint32_t k1,
                                        uint32_t c0, uint32_t c1) {
  uint32_t k2 = k0 ^ k1 ^ 0x1BD11BDAu;
  uint32_t x0 = c0 + k0, x1 = c1 + k1;
  tfr(x0,x1,13); tfr(x0,x1,15); tfr(x0,x1,26); tfr(x0,x1,6);
  x0 += k1; x1 += k2 + 1u;
  tfr(x0,x1,17); tfr(x0,x1,29); tfr(x0,x1,16); tfr(x0,x1,24);
  x0 += k2; x1 += k0 + 2u;
  tfr(x0,x1,13); tfr(x0,x1,15); tfr(x0,x1,26); tfr(x0,x1,6);
  x0 += k0; x1 += k1 + 3u;
  tfr(x0,x1,17); tfr(x0,x1,29); tfr(x0,x1,16); tfr(x0,x1,24);
  x0 += k1; x1 += k2 + 4u;
  tfr(x0,x1,13); tfr(x0,x1,15); tfr(x0,x1,26); tfr(x0,x1,6);
  x0 += k2; x1 += k0 + 5u;
  return make_uint2(x0, x1);
}

__device__ __forceinline__ float bits_to_unif(uint32_t b) {
  return __uint_as_float((b >> 9) | 0x3f800000u) - 1.0f;
}

__global__ __launch_bounds__(512, 4)
void snn_fused(const float* __restrict__ x,  const float* __restrict__ W1,
               const float* __restrict__ b1, const float* __restrict__ W2,
               const float* __restrict__ b2, float* __restrict__ out) {
  __shared__ double   wt[2][TD * WTJ];     // 65536 B, double-buffered [dt][j]
  __shared__ uint32_t xib[2][16][XIW];     // 3328 B  (xi bits for t0,t1)
  __shared__ uint32_t spk[16][SPW];        // 896 B

  const int tid  = threadIdx.x;            // 0..511
  const int g    = blockIdx.x;             // 0..1023
  const int wv   = tid >> 6;               // wave 0..7
  const int sg   = wv >> 1;                // sample group 0..3 (4 samples)
  const int kh   = wv & 1;                 // neuron half: j base 0 / 256
  const int lane = tid & 63;
  const int jb   = 256 * kh + lane;        // neuron j for k=0

  // zero padded j rows (j in [400,512)) in BOTH buffers once
  for (int i = tid; i < 2 * TD * WTJ; i += 512)
    if ((i & (WTJ - 1)) >= HID) (&wt[0][0])[i] = 0.0;

  // biases of owned neurons (j >= 400 dummies stay 0 -> never fire)
  double bb[4];
#pragma unroll
  for (int k = 0; k < 4; ++k) {
    const int j = jb + 64 * k;
    bb[k] = (j < HID) ? (double)b1[j] : 0.0;
  }

  // persistent layer-1 state: samples 4sg+s, neurons j = jb + 64k
  double   mem1[4][4];
  double   acc1[4][4];
  uint32_t spv[4];
#pragma unroll
  for (int s = 0; s < 4; ++s) {
    spv[s] = 0u;
#pragma unroll
    for (int k = 0; k < 4; ++k) { mem1[s][k] = 0.0; acc1[s][k] = 0.0; }
  }

  // layer-2 ownership: tid<160 -> (sample ls, output lo)
  const int ls = tid / ODIM;
  const int lo = tid - ls * ODIM;
  double m2 = 0.0;
  int    s2 = 0, cnt2 = 0;
  const double b2r = (tid < 160) ? (double)b2[lo] : 0.0;

  auto layer2_step = [&]() {
    if (tid < 160) {
      double a2  = s2 ? 0.0 : m2 * 0.2;
      double dot = 0.0;
      for (int ww = 0; ww < 13; ++ww) {
        uint32_t bits = spk[ls][ww];
        if (ww == 12) bits &= 0xFFFFu;     // j in [384,400)
        const int jb2 = 32 * ww;
        while (bits) {
          const int bi = __ffs(bits) - 1;
          bits &= bits - 1u;
          dot += (double)W2[lo * HID + jb2 + bi];
        }
      }
      m2 = (a2 + dot) + b2r;
      s2 = (m2 > 0.5) ? 1 : 0;
      cnt2 += s2;
    }
  };

  // ---- prime the pipeline: buf0 <- tile 0, regs <- tile 1 ----
  const bool stager = (tid < HID);
  float4 va = make_float4(0,0,0,0), vb = va;
  if (stager) {
    const float4* s0 = (const float4*)(W1 + tid * INDIM);
    va = s0[0]; vb = s0[1];                // tile 0 (8 floats)
    double* dst = &wt[0][tid];
    dst[0*WTJ] = (double)va.x;  dst[1*WTJ] = (double)va.y;
    dst[2*WTJ] = (double)va.z;  dst[3*WTJ] = (double)va.w;
    dst[4*WTJ] = (double)vb.x;  dst[5*WTJ] = (double)vb.y;
    dst[6*WTJ] = (double)vb.z;  dst[7*WTJ] = (double)vb.w;
    const float4* s1 = (const float4*)(W1 + tid * INDIM + TD);
    va = s1[0]; vb = s1[1];                // tile 1
  }
  int cur = 0;
  int ld  = 2;                             // next tile index to load (mod NT)
  __syncthreads();                         // buf0 + pad zeros visible

  for (int tp = 0; tp < TSTEPS / 2; ++tp) {
    // ---- step keys for the pair ----
    const uint2 ka = tf2x32(0u, 42u, 0u, (uint32_t)(2 * tp));
    const uint2 kb = tf2x32(0u, 42u, 0u, (uint32_t)(2 * tp + 1));
    const uint32_t kx[2] = { ka.x, kb.x };
    const uint32_t ky[2] = { ka.y, kb.y };

    // ---- xi generation for BOTH steps; c-range split across kh pair ----
    const int cA = kh ? 7 : 0;
    const int cB = kh ? 13 : 7;
    for (int s = 0; s < 4; ++s) {
      const int q   = 4 * sg + s;
      const int row = g * 8 + (q & 7) + ((q >= 8) ? 8192 : 0);
      for (int c = cA; c < cB; ++c) {
        const int d = c * 64 + lane;
        const bool valid = (d < INDIM);
        float xv = 0.0f;
        if (valid) xv = x[row * INDIM + d];
        const uint32_t e = (uint32_t)row * (uint32_t)INDIM + (uint32_t)d;
#pragma unroll
        for (int tt = 0; tt < 2; ++tt) {
          int xb = 0;
          if (valid) {
            uint2 r = tf2x32(kx[tt], ky[tt], 0u, e);
            xb = xv > bits_to_unif(r.x ^ r.y);
          }
          unsigned long long m = __ballot(xb);
          if (lane == 0) {
            xib[tt][q][2*c]     = (uint32_t)m;
            xib[tt][q][2*c + 1] = (uint32_t)(m >> 32);
          }
        }
      }
    }
    __syncthreads();                       // xib visible to both kh waves

    // ---- decay + reset into t0 accumulator; zero t1 accumulator ----
#pragma unroll
    for (int s = 0; s < 4; ++s)
#pragma unroll
      for (int k = 0; k < 4; ++k) {
        mem1[s][k] = ((spv[s] >> k) & 1u) ? 0.0 : mem1[s][k] * 0.2;
        acc1[s][k] = 0.0;
      }

    // ---- ONE sweep over 98 tiles feeds BOTH timesteps (double-buffered) --
    for (int td = 0; td < NT; ++td) {
      // stage tile td+1 into buf^1 (overlaps consume of buf), then
      // prefetch tile 'ld' from global (lands during next consume phase)
      if (stager) {
        double* dst = &wt[cur ^ 1][tid];
        dst[0*WTJ] = (double)va.x;  dst[1*WTJ] = (double)va.y;
        dst[2*WTJ] = (double)va.z;  dst[3*WTJ] = (double)va.w;
        dst[4*WTJ] = (double)vb.x;  dst[5*WTJ] = (double)vb.y;
        dst[6*WTJ] = (double)vb.z;  dst[7*WTJ] = (double)vb.w;
        const float4* src = (const float4*)(W1 + tid * INDIM + ld * TD);
        va = src[0]; vb = src[1];
      }
      ld = (ld + 1 == NT) ? 0 : ld + 1;

      // xi bit-words for this tile, hoisted to SGPR (wave-uniform)
      const int wi = td >> 2, sh = (td & 3) * 8;
      uint32_t bA[4], bB[4];
#pragma unroll
      for (int s = 0; s < 4; ++s) {
        bA[s] = (uint32_t)__builtin_amdgcn_readfirstlane(
                  (int)((xib[0][4*sg + s][wi] >> sh) & 0xFFu));
        bB[s] = (uint32_t)__builtin_amdgcn_readfirstlane(
                  (int)((xib[1][4*sg + s][wi] >> sh) & 0xFFu));
      }

      const double* wp = &wt[cur][jb];
#pragma unroll
      for (int dt = 0; dt < TD; ++dt) {
        double wd[4];
#pragma unroll
        for (int k = 0; k < 4; ++k)
          wd[k] = wp[dt * WTJ + 64 * k];   // ds_read_b64, conflict-free
#pragma unroll
        for (int s = 0; s < 4; ++s) {
          if (bA[s] & (1u << dt)) {        // scalar test: s_and + s_cbranch
#pragma unroll
            for (int k = 0; k < 4; ++k) mem1[s][k] += wd[k];
          }
          if (bB[s] & (1u << dt)) {
#pragma unroll
            for (int k = 0; k < 4; ++k) acc1[s][k] += wd[k];
          }
        }
      }
      __syncthreads();                     // buf consumed; buf^1 ready
      cur ^= 1;
    }

    // ---- finalize t0: + b1, threshold, pack spikes ----
#pragma unroll
    for (int s = 0; s < 4; ++s) {
      uint32_t m = 0u;
#pragma unroll
      for (int k = 0; k < 4; ++k) {
        mem1[s][k] += bb[k];
        if (mem1[s][k] > 0.5) m |= (1u << k);
      }
      spv[s] = m;
#pragma unroll
      for (int k = 0; k < 4; ++k) {
        unsigned long long bm = __ballot((m >> k) & 1u);
        const int w0 = 8 * kh + 2 * k;
        if (lane == 0 && w0 < SPW) {
          spk[4*sg + s][w0]     = (uint32_t)bm;
          spk[4*sg + s][w0 + 1] = (uint32_t)(bm >> 32);
        }
      }
    }
    __syncthreads();                       // spikes(t0) visible
    layer2_step();                         // t0
    __syncthreads();                       // spk consumed

    // ---- finalize t1: decay(t0) + acc1 + b1, threshold, pack ----
#pragma unroll
    for (int s = 0; s < 4; ++s) {
      uint32_t m = 0u;
#pragma unroll
      for (int k = 0; k < 4; ++k) {
        double v = ((spv[s] >> k) & 1u) ? 0.0 : mem1[s][k] * 0.2;
        v += acc1[s][k];
        v += bb[k];
        mem1[s][k] = v;
        if (v > 0.5) m |= (1u << k);
      }
      spv[s] = m;
#pragma unroll
      for (int k = 0; k < 4; ++k) {
        unsigned long long bm = __ballot((m >> k) & 1u);
        const int w0 = 8 * kh + 2 * k;
        if (lane == 0 && w0 < SPW) {
          spk[4*sg + s][w0]     = (uint32_t)bm;
          spk[4*sg + s][w0 + 1] = (uint32_t)(bm >> 32);
        }
      }
    }
    __syncthreads();                       // spikes(t1) visible
    layer2_step();                         // t1
    // next pair: xi-gen then its barrier protect xib/spk before reuse
  }

  // ---- output: h2_sum / 20 ----
  if (tid < 160) {
    const int row = g * 8 + (ls & 7) + ((ls >= 8) ? 8192 : 0);
    out[row * ODIM + lo] = (float)((double)cnt2 / 20.0);
  }
}

extern "C" void kernel_launch(void* const* d_in, const int* in_sizes, int n_in,
                              void* d_out, int out_size, void* d_ws, size_t ws_size,
                              hipStream_t stream) {
  const float* x  = (const float*)d_in[0];
  const float* W1 = (const float*)d_in[1];
  const float* b1 = (const float*)d_in[2];
  const float* W2 = (const float*)d_in[3];
  const float* b2 = (const float*)d_in[4];
  // d_in[5] = time_window (int, ==20) — compile-time constant here.
  float* out = (float*)d_out;
  hipLaunchKernelGGL(snn_fused, dim3(1024), dim3(512), 0, stream,
                     x, W1, b1, W2, b2, out);
}

// Round 3
// 5076.109 us; speedup vs baseline: 1.0511x; 1.0511x over previous
//
#include <hip/hip_runtime.h>
#include <stdint.h>

// ---------------------------------------------------------------------------
// Fused spiking-MLP forward: 20 timesteps, B=16384, 784 -> 400 -> 10.
//
// RNG: jax threefry, PARTITIONABLE semantics (verified absmax 0.0):
//   key_t = TF((0,42),(0,t)); per element e: bits = x0^x1 of TF(key_t,(0,e));
//   u = bitcast((bits>>9)|0x3f800000)-1.0f; xi = (x > u).
//
// V4 (vs V3 @5335us). Profiling accounting found two stall sources:
//  * Layer 2's while(ffs) loop was ~200 SERIAL dependent L2 loads per step
//    (vmcnt-drain each iteration) between two full-block barriers: ~50K
//    cycles/step stalled. Rewritten DENSE over all 400 j in ascending order
//    (identical summation order as the ffs scan -> bit-identical), float4
//    W2 loads fully pipelined, gating via fma(w, (double)bit, dot) which is
//    exact for bit in {0,1}.
//  * wd ds_read latency exposed every dt (branches block scheduler motion).
//    Now depth-1 software-pipelined: dt+1's 4 doubles load during dt's
//    gated adds. Next tile's xi masks likewise computed at the end of the
//    current tile's compute.
// Core structure as V3: TD=8 f64 double-buffered W1 tile, one barrier per
// tile, two timesteps share one sweep, 8 waves = 4 sample-groups x 2
// neuron-halves, SGPR-hoisted xi bits -> scalar-branch-gated f64 adds.
// ---------------------------------------------------------------------------

#define BSZ    16384
#define INDIM  784
#define HID    400
#define ODIM   10
#define TSTEPS 20

#define TD   8            // d-tile size
#define NT   98           // 784/8 tiles per sweep
#define WTJ  512          // padded neuron rows in LDS tile (400 real)
#define XIW  26           // xi words per sample
#define SPW  14           // spike words per sample

__device__ __forceinline__ void tfr(uint32_t& x0, uint32_t& x1, int r) {
  x0 += x1;
  x1 = (x1 << r) | (x1 >> (32 - r));
  x1 ^= x0;
}

__device__ __forceinline__ uint2 tf2x32(uint32_t k0, uint32_t k1,
                                        uint32_t c0, uint32_t c1) {
  uint32_t k2 = k0 ^ k1 ^ 0x1BD11BDAu;
  uint32_t x0 = c0 + k0, x1 = c1 + k1;
  tfr(x0,x1,13); tfr(x0,x1,15); tfr(x0,x1,26); tfr(x0,x1,6);
  x0 += k1; x1 += k2 + 1u;
  tfr(x0,x1,17); tfr(x0,x1,29); tfr(x0,x1,16); tfr(x0,x1,24);
  x0 += k2; x1 += k0 + 2u;
  tfr(x0,x1,13); tfr(x0,x1,15); tfr(x0,x1,26); tfr(x0,x1,6);
  x0 += k0; x1 += k1 + 3u;
  tfr(x0,x1,17); tfr(x0,x1,29); tfr(x0,x1,16); tfr(x0,x1,24);
  x0 += k1; x1 += k2 + 4u;
  tfr(x0,x1,13); tfr(x0,x1,15); tfr(x0,x1,26); tfr(x0,x1,6);
  x0 += k2; x1 += k0 + 5u;
  return make_uint2(x0, x1);
}

__device__ __forceinline__ float bits_to_unif(uint32_t b) {
  return __uint_as_float((b >> 9) | 0x3f800000u) - 1.0f;
}

__global__ __launch_bounds__(512, 4)
void snn_fused(const float* __restrict__ x,  const float* __restrict__ W1,
               const float* __restrict__ b1, const float* __restrict__ W2,
               const float* __restrict__ b2, float* __restrict__ out) {
  __shared__ double   wt[2][TD * WTJ];     // 65536 B, double-buffered [dt][j]
  __shared__ uint32_t xib[2][16][XIW];     // 3328 B  (xi bits for t0,t1)
  __shared__ uint32_t spk[16][SPW];        // 896 B

  const int tid  = threadIdx.x;            // 0..511
  const int g    = blockIdx.x;             // 0..1023
  const int wv   = tid >> 6;               // wave 0..7
  const int sg   = wv >> 1;                // sample group 0..3 (4 samples)
  const int kh   = wv & 1;                 // neuron half: j base 0 / 256
  const int lane = tid & 63;
  const int jb   = 256 * kh + lane;        // neuron j for k=0

  // zero padded j rows (j in [400,512)) in BOTH buffers once
  for (int i = tid; i < 2 * TD * WTJ; i += 512)
    if ((i & (WTJ - 1)) >= HID) (&wt[0][0])[i] = 0.0;

  // biases of owned neurons (j >= 400 dummies stay 0 -> never fire)
  double bb[4];
#pragma unroll
  for (int k = 0; k < 4; ++k) {
    const int j = jb + 64 * k;
    bb[k] = (j < HID) ? (double)b1[j] : 0.0;
  }

  // persistent layer-1 state: samples 4sg+s, neurons j = jb + 64k
  double   mem1[4][4];
  double   acc1[4][4];
  uint32_t spv[4];
#pragma unroll
  for (int s = 0; s < 4; ++s) {
    spv[s] = 0u;
#pragma unroll
    for (int k = 0; k < 4; ++k) { mem1[s][k] = 0.0; acc1[s][k] = 0.0; }
  }

  // layer-2 ownership: tid<160 -> (sample ls, output lo)
  const int ls = tid / ODIM;
  const int lo = tid - ls * ODIM;
  double m2 = 0.0;
  int    s2 = 0, cnt2 = 0;
  const double b2r = (tid < 160) ? (double)b2[lo] : 0.0;

  // Dense branchless layer-2: ascending-j gated adds (same order the old
  // ffs scan produced -> bit-identical). fma(w, bit, dot) is exact for
  // bit in {0,1}. float4 loads pipeline freely (no dependent control).
  auto layer2_step = [&]() {
    if (tid < 160) {
      double a2  = s2 ? 0.0 : m2 * 0.2;
      double dot = 0.0;
      const float4* w2p = (const float4*)(W2 + lo * HID);
      for (int m = 0; m < 12; ++m) {       // words 0..11 -> j 0..383
        const uint32_t word = spk[ls][m];
#pragma unroll
        for (int q = 0; q < 8; ++q) {
          const float4 v4 = w2p[8 * m + q];
          const float wf[4] = { v4.x, v4.y, v4.z, v4.w };
#pragma unroll
          for (int e = 0; e < 4; ++e) {
            const double bit = (double)((word >> (4 * q + e)) & 1u);
            dot = fma((double)wf[e], bit, dot);
          }
        }
      }
      {                                    // word 12, j 384..399 (16 bits)
        const uint32_t word = spk[ls][12];
#pragma unroll
        for (int q = 0; q < 4; ++q) {
          const float4 v4 = w2p[96 + q];
          const float wf[4] = { v4.x, v4.y, v4.z, v4.w };
#pragma unroll
          for (int e = 0; e < 4; ++e) {
            const double bit = (double)((word >> (4 * q + e)) & 1u);
            dot = fma((double)wf[e], bit, dot);
          }
        }
      }
      m2 = (a2 + dot) + b2r;
      s2 = (m2 > 0.5) ? 1 : 0;
      cnt2 += s2;
    }
  };

  // ---- prime the pipeline: buf0 <- tile 0, regs <- tile 1 ----
  const bool stager = (tid < HID);
  float4 va = make_float4(0,0,0,0), vb = va;
  if (stager) {
    const float4* s0 = (const float4*)(W1 + tid * INDIM);
    va = s0[0]; vb = s0[1];                // tile 0 (8 floats)
    double* dst = &wt[0][tid];
    dst[0*WTJ] = (double)va.x;  dst[1*WTJ] = (double)va.y;
    dst[2*WTJ] = (double)va.z;  dst[3*WTJ] = (double)va.w;
    dst[4*WTJ] = (double)vb.x;  dst[5*WTJ] = (double)vb.y;
    dst[6*WTJ] = (double)vb.z;  dst[7*WTJ] = (double)vb.w;
    const float4* s1 = (const float4*)(W1 + tid * INDIM + TD);
    va = s1[0]; vb = s1[1];                // tile 1
  }
  int cur = 0;
  int ld  = 2;                             // next tile index to load (mod NT)
  __syncthreads();                         // buf0 + pad zeros visible

  for (int tp = 0; tp < TSTEPS / 2; ++tp) {
    // ---- step keys for the pair ----
    const uint2 ka = tf2x32(0u, 42u, 0u, (uint32_t)(2 * tp));
    const uint2 kb = tf2x32(0u, 42u, 0u, (uint32_t)(2 * tp + 1));
    const uint32_t kx[2] = { ka.x, kb.x };
    const uint32_t ky[2] = { ka.y, kb.y };

    // ---- xi generation for BOTH steps; c-range split across kh pair ----
    const int cA = kh ? 7 : 0;
    const int cB = kh ? 13 : 7;
    for (int s = 0; s < 4; ++s) {
      const int q   = 4 * sg + s;
      const int row = g * 8 + (q & 7) + ((q >= 8) ? 8192 : 0);
      for (int c = cA; c < cB; ++c) {
        const int d = c * 64 + lane;
        const bool valid = (d < INDIM);
        float xv = 0.0f;
        if (valid) xv = x[row * INDIM + d];
        const uint32_t e = (uint32_t)row * (uint32_t)INDIM + (uint32_t)d;
#pragma unroll
        for (int tt = 0; tt < 2; ++tt) {
          int xb = 0;
          if (valid) {
            uint2 r = tf2x32(kx[tt], ky[tt], 0u, e);
            xb = xv > bits_to_unif(r.x ^ r.y);
          }
          unsigned long long m = __ballot(xb);
          if (lane == 0) {
            xib[tt][q][2*c]     = (uint32_t)m;
            xib[tt][q][2*c + 1] = (uint32_t)(m >> 32);
          }
        }
      }
    }
    __syncthreads();                       // xib visible to both kh waves

    // ---- decay + reset into t0 accumulator; zero t1 accumulator ----
#pragma unroll
    for (int s = 0; s < 4; ++s)
#pragma unroll
      for (int k = 0; k < 4; ++k) {
        mem1[s][k] = ((spv[s] >> k) & 1u) ? 0.0 : mem1[s][k] * 0.2;
        acc1[s][k] = 0.0;
      }

    // ---- masks for tile 0 of the sweep ----
    uint32_t bA[4], bB[4];
#pragma unroll
    for (int s = 0; s < 4; ++s) {
      bA[s] = (uint32_t)__builtin_amdgcn_readfirstlane(
                (int)((xib[0][4*sg + s][0] >> 0) & 0xFFu));
      bB[s] = (uint32_t)__builtin_amdgcn_readfirstlane(
                (int)((xib[1][4*sg + s][0] >> 0) & 0xFFu));
    }

    // ---- ONE sweep over 98 tiles feeds BOTH timesteps (double-buffered) --
    for (int td = 0; td < NT; ++td) {
      // stage tile td+1 into buf^1 (overlaps consume of buf), then
      // prefetch tile 'ld' from global (lands during next consume phase)
      if (stager) {
        double* dst = &wt[cur ^ 1][tid];
        dst[0*WTJ] = (double)va.x;  dst[1*WTJ] = (double)va.y;
        dst[2*WTJ] = (double)va.z;  dst[3*WTJ] = (double)va.w;
        dst[4*WTJ] = (double)vb.x;  dst[5*WTJ] = (double)vb.y;
        dst[6*WTJ] = (double)vb.z;  dst[7*WTJ] = (double)vb.w;
        const float4* src = (const float4*)(W1 + tid * INDIM + ld * TD);
        va = src[0]; vb = src[1];
      }
      ld = (ld + 1 == NT) ? 0 : ld + 1;

      const double* wp = &wt[cur][jb];

      // depth-1 software pipeline on wd: read dt+1 during dt's gated adds
      double wdc[4];
#pragma unroll
      for (int k = 0; k < 4; ++k) wdc[k] = wp[64 * k];

#pragma unroll
      for (int dt = 0; dt < TD; ++dt) {
        double wdn[4];
        if (dt + 1 < TD) {
#pragma unroll
          for (int k = 0; k < 4; ++k) wdn[k] = wp[(dt + 1) * WTJ + 64 * k];
        }
#pragma unroll
        for (int s = 0; s < 4; ++s) {
          if (bA[s] & (1u << dt)) {        // scalar test: s_and + s_cbranch
#pragma unroll
            for (int k = 0; k < 4; ++k) mem1[s][k] += wdc[k];
          }
          if (bB[s] & (1u << dt)) {
#pragma unroll
            for (int k = 0; k < 4; ++k) acc1[s][k] += wdc[k];
          }
        }
        if (dt + 1 < TD) {
#pragma unroll
          for (int k = 0; k < 4; ++k) wdc[k] = wdn[k];
        }
      }

      // masks for NEXT tile (xib is stable through the sweep) — off the
      // critical path: overlaps the tail of compute, before the barrier.
      const int tn = td + 1;               // tn==NT reads word 24 (valid mem)
      const int wi = tn >> 2, sh = (tn & 3) * 8;
#pragma unroll
      for (int s = 0; s < 4; ++s) {
        bA[s] = (uint32_t)__builtin_amdgcn_readfirstlane(
                  (int)((xib[0][4*sg + s][wi] >> sh) & 0xFFu));
        bB[s] = (uint32_t)__builtin_amdgcn_readfirstlane(
                  (int)((xib[1][4*sg + s][wi] >> sh) & 0xFFu));
      }

      __syncthreads();                     // buf consumed; buf^1 ready
      cur ^= 1;
    }

    // ---- finalize t0: + b1, threshold, pack spikes ----
#pragma unroll
    for (int s = 0; s < 4; ++s) {
      uint32_t m = 0u;
#pragma unroll
      for (int k = 0; k < 4; ++k) {
        mem1[s][k] += bb[k];
        if (mem1[s][k] > 0.5) m |= (1u << k);
      }
      spv[s] = m;
#pragma unroll
      for (int k = 0; k < 4; ++k) {
        unsigned long long bm = __ballot((m >> k) & 1u);
        const int w0 = 8 * kh + 2 * k;
        if (lane == 0 && w0 < SPW) {
          spk[4*sg + s][w0]     = (uint32_t)bm;
          spk[4*sg + s][w0 + 1] = (uint32_t)(bm >> 32);
        }
      }
    }
    __syncthreads();                       // spikes(t0) visible
    layer2_step();                         // t0
    __syncthreads();                       // spk consumed

    // ---- finalize t1: decay(t0) + acc1 + b1, threshold, pack ----
#pragma unroll
    for (int s = 0; s < 4; ++s) {
      uint32_t m = 0u;
#pragma unroll
      for (int k = 0; k < 4; ++k) {
        double v = ((spv[s] >> k) & 1u) ? 0.0 : mem1[s][k] * 0.2;
        v += acc1[s][k];
        v += bb[k];
        mem1[s][k] = v;
        if (v > 0.5) m |= (1u << k);
      }
      spv[s] = m;
#pragma unroll
      for (int k = 0; k < 4; ++k) {
        unsigned long long bm = __ballot((m >> k) & 1u);
        const int w0 = 8 * kh + 2 * k;
        if (lane == 0 && w0 < SPW) {
          spk[4*sg + s][w0]     = (uint32_t)bm;
          spk[4*sg + s][w0 + 1] = (uint32_t)(bm >> 32);
        }
      }
    }
    __syncthreads();                       // spikes(t1) visible
    layer2_step();                         // t1
    // next pair: xi-gen then its barrier protect xib/spk before reuse
  }

  // ---- output: h2_sum / 20 ----
  if (tid < 160) {
    const int row = g * 8 + (ls & 7) + ((ls >= 8) ? 8192 : 0);
    out[row * ODIM + lo] = (float)((double)cnt2 / 20.0);
  }
}

extern "C" void kernel_launch(void* const* d_in, const int* in_sizes, int n_in,
                              void* d_out, int out_size, void* d_ws, size_t ws_size,
                              hipStream_t stream) {
  const float* x  = (const float*)d_in[0];
  const float* W1 = (const float*)d_in[1];
  const float* b1 = (const float*)d_in[2];
  const float* W2 = (const float*)d_in[3];
  const float* b2 = (const float*)d_in[4];
  // d_in[5] = time_window (int, ==20) — compile-time constant here.
  float* out = (float*)d_out;
  hipLaunchKernelGGL(snn_fused, dim3(1024), dim3(512), 0, stream,
                     x, W1, b1, W2, b2, out);
}